// Round 1
// baseline (646.476 us; speedup 1.0000x reference)
//
#include <hip/hip_runtime.h>
#include <math.h>

#define N_SRC   200000
#define N_DST   50000
#define N_EDGES 800000
#define N_IN    256
#define N_OUT   128
// note: 2*N_OUT == 256 == N_IN, and out rows are 256 floats

// workspace layout (bytes)
#define WS_COUNTS   0          // int[51200] (zeroed; uses 50001)
#define WS_CURSOR   204800     // int[51200] (zeroed; uses 50000)
#define WS_OFFSETS  409600     // int[50001]
#define WS_CSRCOL   614400     // int[800000]
#define WS_CSRVAL   3814400    // float[800000]
// total ~7.02 MB

__global__ void k_hist(const int* __restrict__ rows, int* __restrict__ counts) {
    int i = blockIdx.x * 256 + threadIdx.x;
    if (i < N_EDGES) atomicAdd(&counts[rows[i]], 1);
}

// single-block exclusive scan over N_DST+1 entries (1024 threads, 16 waves)
__global__ void k_scan(const int* __restrict__ counts, int* __restrict__ offsets) {
    __shared__ int wsum[16];
    __shared__ int s_carry;
    const int tid = threadIdx.x;
    if (tid == 0) s_carry = 0;
    __syncthreads();
    const int lane = tid & 63, wid = tid >> 6;
    const int n = N_DST + 1;
    for (int base = 0; base < n; base += 1024) {
        int i = base + tid;
        int v = (i < n) ? counts[i] : 0;
        int s = v;
        #pragma unroll
        for (int o = 1; o < 64; o <<= 1) { int t = __shfl_up(s, o, 64); if (lane >= o) s += t; }
        if (lane == 63) wsum[wid] = s;
        __syncthreads();
        if (wid == 0 && lane < 16) {
            int w = wsum[lane];
            #pragma unroll
            for (int o = 1; o < 16; o <<= 1) { int t = __shfl_up(w, o, 64); if (lane >= o) w += t; }
            wsum[lane] = w;
        }
        __syncthreads();
        int incl = s + (wid > 0 ? wsum[wid - 1] : 0);
        if (i < n) offsets[i] = incl - v + s_carry;
        __syncthreads();
        if (tid == 1023) s_carry += incl;
        __syncthreads();
    }
}

__global__ void k_scatter(const int* __restrict__ rows, const int* __restrict__ cols,
                          const float* __restrict__ vals, const int* __restrict__ offsets,
                          int* __restrict__ cursor, int* __restrict__ csr_col,
                          float* __restrict__ csr_val) {
    int i = blockIdx.x * 256 + threadIdx.x;
    if (i < N_EDGES) {
        int r = rows[i];
        int p = offsets[r] + atomicAdd(&cursor[r], 1);
        csr_col[p] = cols[i];
        csr_val[p] = vals[i];
    }
}

// one block (4 waves) per dst row; lane -> float4 chunk of the 256 features.
// feat is written into `out` (d_out) — overwritten in-place by k_fused later.
__global__ __launch_bounds__(256) void k_spmm(
        const float* __restrict__ x, const int* __restrict__ offsets,
        const int* __restrict__ csr_col, const float* __restrict__ csr_val,
        float* __restrict__ out) {
    const int row = blockIdx.x;
    const int tid = threadIdx.x, lane = tid & 63, wid = tid >> 6;
    const int start = offsets[row], end = offsets[row + 1];
    const float4* __restrict__ x4 = (const float4*)x;
    float4 acc = make_float4(0.f, 0.f, 0.f, 0.f);
    for (int e = start + wid; e < end; e += 4) {
        int c = csr_col[e];
        float v = csr_val[e];
        float4 xv = x4[(long)c * 64 + lane];
        acc.x = fmaf(v, xv.x, acc.x);
        acc.y = fmaf(v, xv.y, acc.y);
        acc.z = fmaf(v, xv.z, acc.z);
        acc.w = fmaf(v, xv.w, acc.w);
    }
    __shared__ float4 red[4][64];
    red[wid][lane] = acc;
    __syncthreads();
    if (wid == 0) {
        float4 a = red[0][lane], b = red[1][lane], c = red[2][lane], d = red[3][lane];
        float4 s;
        s.x = a.x + b.x + c.x + d.x;
        s.y = a.y + b.y + c.y + d.y;
        s.z = a.z + b.z + c.z + d.z;
        s.w = a.w + b.w + c.w + d.w;
        ((float4*)out)[(long)row * 64 + lane] = s;
    }
}

// fused: dual matvec (self: x[sn]@W_b+b_b -> cols 0..127; neigh: feat@W_w+b_w
// -> cols 128..255), ELU, row layernorm + affine. 8 rows per block, thread=col.
#define RROWS 8
__global__ __launch_bounds__(256) void k_fused(
        const float* __restrict__ x, const int* __restrict__ sn,
        const float* __restrict__ Ww, const float* __restrict__ bw,
        const float* __restrict__ Wb, const float* __restrict__ bb,
        const float* __restrict__ scale, const float* __restrict__ offs,
        float* __restrict__ out) {
    __shared__ float As[N_IN][RROWS];   // x[sampled] rows, transposed
    __shared__ float Af[N_IN][RROWS];   // feat rows, transposed
    __shared__ float red[RROWS][256];
    __shared__ float mean_s[RROWS], rstd_s[RROWS];
    const int tid = threadIdx.x;
    const int row0 = blockIdx.x * RROWS;

    #pragma unroll
    for (int r = 0; r < RROWS; r++) {
        int sr = sn[row0 + r];
        As[tid][r] = x[(long)sr * N_IN + tid];
        Af[tid][r] = out[(long)(row0 + r) * 256 + tid];   // feat staged in d_out
    }
    __syncthreads();

    const bool self = tid < 128;
    const int j = self ? tid : tid - 128;
    const float* __restrict__ W = self ? Wb : Ww;
    const float bias = self ? bb[j] : bw[j];
    const float* A = self ? &As[0][0] : &Af[0][0];

    float acc[RROWS];
    #pragma unroll
    for (int r = 0; r < RROWS; r++) acc[r] = bias;

    #pragma unroll 4
    for (int k = 0; k < N_IN; k++) {
        float w = W[k * 128 + j];
        #pragma unroll
        for (int r = 0; r < RROWS; r++) acc[r] = fmaf(A[k * RROWS + r], w, acc[r]);
    }

    float e[RROWS];
    #pragma unroll
    for (int r = 0; r < RROWS; r++) e[r] = acc[r] > 0.f ? acc[r] : expm1f(acc[r]);

    #pragma unroll
    for (int r = 0; r < RROWS; r++) red[r][tid] = e[r];
    __syncthreads();

    const int rg = tid >> 5, l32 = tid & 31;
    float s = 0.f, s2 = 0.f;
    #pragma unroll
    for (int c = l32; c < 256; c += 32) { float v = red[rg][c]; s += v; s2 += v * v; }
    #pragma unroll
    for (int o = 16; o > 0; o >>= 1) {
        s  += __shfl_down(s,  o, 32);
        s2 += __shfl_down(s2, o, 32);
    }
    if (l32 == 0) {
        float m = s * (1.f / 256.f);
        float var = s2 * (1.f / 256.f) - m * m;
        mean_s[rg] = m;
        rstd_s[rg] = rsqrtf(var + 1e-9f);
    }
    __syncthreads();

    float sc = scale[tid], of = offs[tid];
    #pragma unroll
    for (int r = 0; r < RROWS; r++)
        out[(long)(row0 + r) * 256 + tid] = (e[r] - mean_s[r]) * rstd_s[r] * sc + of;
}

extern "C" void kernel_launch(void* const* d_in, const int* in_sizes, int n_in,
                              void* d_out, int out_size, void* d_ws, size_t ws_size,
                              hipStream_t stream) {
    const float* x     = (const float*)d_in[0];
    const int*   erows = (const int*)  d_in[1];
    const int*   ecols = (const int*)  d_in[2];
    const float* evals = (const float*)d_in[3];
    const int*   sn    = (const int*)  d_in[4];
    const float* Ww    = (const float*)d_in[5];
    const float* bw    = (const float*)d_in[6];
    const float* Wb    = (const float*)d_in[7];
    const float* bb    = (const float*)d_in[8];
    const float* scale = (const float*)d_in[9];
    const float* offs  = (const float*)d_in[10];
    float* out = (float*)d_out;

    char* ws = (char*)d_ws;
    int*   counts  = (int*)  (ws + WS_COUNTS);
    int*   cursor  = (int*)  (ws + WS_CURSOR);
    int*   offsets = (int*)  (ws + WS_OFFSETS);
    int*   csr_col = (int*)  (ws + WS_CSRCOL);
    float* csr_val = (float*)(ws + WS_CSRVAL);

    // zero counts + cursor (ws is poisoned 0xAA before every call)
    hipMemsetAsync(ws, 0, WS_OFFSETS, stream);

    k_hist   <<<(N_EDGES + 255) / 256, 256, 0, stream>>>(erows, counts);
    k_scan   <<<1, 1024, 0, stream>>>(counts, offsets);
    k_scatter<<<(N_EDGES + 255) / 256, 256, 0, stream>>>(erows, ecols, evals, offsets,
                                                         cursor, csr_col, csr_val);
    k_spmm   <<<N_DST, 256, 0, stream>>>(x, offsets, csr_col, csr_val, out);
    k_fused  <<<N_DST / RROWS, 256, 0, stream>>>(x, sn, Ww, bw, Wb, bb, scale, offs, out);
}

// Round 2
// 539.375 us; speedup vs baseline: 1.1986x; 1.1986x over previous
//
#include <hip/hip_runtime.h>
#include <math.h>

#define N_SRC   200000
#define N_DST   50000
#define N_EDGES 800000
#define N_IN    256
#define N_OUT   128

// ---- workspace layout (bytes) ----
#define WS_COUNTS   0          // int[51200]
#define WS_CURSOR   204800     // int[51200]
#define WS_OFFSETS  409600     // int[50001+pad]
#define WS_CSRCOL   614400     // int[800000]
#define WS_CSRVAL   3814400    // float[800000]
#define WS_BSUM     7014400    // int[64]
#define WS_WTW      7014656    // ushort[128*256] bf16 (W_w transposed)
#define WS_WTB      7080192    // ushort[128*256] bf16 (W_b transposed)
#define WS_NEIGH    7145728    // ushort[50000*128] bf16
#define WS_SELF     19945728   // ushort[50000*128] bf16
// total ~32.8 MB

typedef short  bf16x8 __attribute__((ext_vector_type(8)));
typedef unsigned short u16x8 __attribute__((ext_vector_type(8)));
typedef float  f32x4  __attribute__((ext_vector_type(4)));

__device__ inline unsigned short f2bf(float f) {
    unsigned u = __builtin_bit_cast(unsigned, f);
    u += 0x7fffu + ((u >> 16) & 1u);           // RNE
    return (unsigned short)(u >> 16);
}
__device__ inline float bf2f(unsigned short h) {
    return __builtin_bit_cast(float, (unsigned)h << 16);
}

// ---------------- CSR build ----------------
__global__ void k_hist(const int* __restrict__ rows, int* __restrict__ counts) {
    int i = blockIdx.x * 256 + threadIdx.x;
    if (i < N_EDGES) atomicAdd(&counts[rows[i]], 1);
}

// 3-phase scan over N_DST+1 = 50001 entries, 1024 elems/block, 49 blocks
__global__ __launch_bounds__(256) void k_scan1(const int* __restrict__ counts,
                                               int* __restrict__ offsets,
                                               int* __restrict__ bsum) {
    __shared__ int wtot[4];
    const int tid = threadIdx.x, lane = tid & 63, wid = tid >> 6;
    const int base = blockIdx.x * 1024 + tid * 4;
    int c0 = (base + 0 < 50001) ? counts[base + 0] : 0;
    int c1 = (base + 1 < 50001) ? counts[base + 1] : 0;
    int c2 = (base + 2 < 50001) ? counts[base + 2] : 0;
    int c3 = (base + 3 < 50001) ? counts[base + 3] : 0;
    int ts = c0 + c1 + c2 + c3;
    int s = ts;
    #pragma unroll
    for (int o = 1; o < 64; o <<= 1) { int t = __shfl_up(s, o, 64); if (lane >= o) s += t; }
    if (lane == 63) wtot[wid] = s;
    __syncthreads();
    int woff = 0;
    #pragma unroll
    for (int w = 0; w < 4; w++) if (w < wid) woff += wtot[w];
    int e0 = woff + s - ts;
    if (base + 0 < 50001) offsets[base + 0] = e0;
    if (base + 1 < 50001) offsets[base + 1] = e0 + c0;
    if (base + 2 < 50001) offsets[base + 2] = e0 + c0 + c1;
    if (base + 3 < 50001) offsets[base + 3] = e0 + c0 + c1 + c2;
    if (tid == 255) bsum[blockIdx.x] = wtot[0] + wtot[1] + wtot[2] + wtot[3];
}

__global__ void k_scan2(int* __restrict__ bsum) {
    const int lane = threadIdx.x;           // 64 threads, 1 block
    int v = (lane < 49) ? bsum[lane] : 0;
    int s = v;
    #pragma unroll
    for (int o = 1; o < 64; o <<= 1) { int t = __shfl_up(s, o, 64); if (lane >= o) s += t; }
    if (lane < 49) bsum[lane] = s - v;      // exclusive
}

__global__ __launch_bounds__(256) void k_scan3(int* __restrict__ offsets,
                                               const int* __restrict__ bsum) {
    const int off = bsum[blockIdx.x];
    const int base = blockIdx.x * 1024 + threadIdx.x * 4;
    #pragma unroll
    for (int j = 0; j < 4; j++)
        if (base + j < 50001) offsets[base + j] += off;
}

__global__ void k_scatter(const int* __restrict__ rows, const int* __restrict__ cols,
                          const float* __restrict__ vals, const int* __restrict__ offsets,
                          int* __restrict__ cursor, int* __restrict__ csr_col,
                          float* __restrict__ csr_val) {
    int i = blockIdx.x * 256 + threadIdx.x;
    if (i < N_EDGES) {
        int r = rows[i];
        int p = offsets[r] + atomicAdd(&cursor[r], 1);
        csr_col[p] = cols[i];
        csr_val[p] = vals[i];
    }
}

// ---------------- weight prep: Wt[n][k] = bf16(W[k][n]) ----------------
__global__ __launch_bounds__(256) void k_wprep(const float* __restrict__ Ww,
                                               const float* __restrict__ Wb,
                                               unsigned short* __restrict__ Wtw,
                                               unsigned short* __restrict__ Wtb) {
    int tot = blockIdx.x * 256 + threadIdx.x;      // 65536 threads
    int sel = tot >> 15;
    int idx = tot & 32767;
    int n = idx >> 8, k = idx & 255;
    const float* src = sel ? Wb : Ww;
    unsigned short* dst = sel ? Wtb : Wtw;
    dst[n * 256 + k] = f2bf(src[k * 128 + n]);
}

// ---------------- MFMA GEMM: Y[m][0:128) = bf16( A[row(m)][0:256) @ W ) ----------------
// A f32 row-major [*,256]; Bt bf16 [128 n][256 k]; Y bf16 [M][128].
// Block: 64 M-rows, 256 threads (4 waves; wave w -> rows w*16..w*16+16).
#define LDT 88          // padded LDS row stride (bf16 elems)
#define EPS 132         // epilogue LDS stride
__global__ __launch_bounds__(256) void k_gemm(const float* __restrict__ A,
                                              const int* __restrict__ rowidx,
                                              const unsigned short* __restrict__ Bt,
                                              unsigned short* __restrict__ Y,
                                              int M) {
    __shared__ __align__(16) unsigned short smA[64 * LDT];
    __shared__ __align__(16) unsigned short smB[128 * LDT];
    const int tid = threadIdx.x;
    const int lane = tid & 63, wid = tid >> 6;
    const int l15 = lane & 15, quad = lane >> 4;
    const int row0 = blockIdx.x * 64;

    // A-staging coords: thread -> (row r, 16-f32 segment)
    const int ar = tid >> 2, aseg = (tid & 3) * 16;
    int srow = row0 + ar;
    if (srow >= M) srow = M - 1;
    if (rowidx) srow = rowidx[srow];
    const float* aptr = A + (long)srow * 256 + aseg;
    // B-staging coords: thread -> (n row, 32-elem half)
    const int bn = tid >> 1, bhalf = (tid & 1) * 32;
    const unsigned short* bptr = Bt + (long)bn * 256 + bhalf;

    f32x4 acc[8];
    #pragma unroll
    for (int t = 0; t < 8; t++) acc[t] = (f32x4){0.f, 0.f, 0.f, 0.f};

    for (int kt = 0; kt < 4; kt++) {
        const int k0 = kt * 64;
        // stage A (convert f32->bf16)
        {
            const float4* s4 = (const float4*)(aptr + k0);
            float4 v0 = s4[0], v1 = s4[1], v2 = s4[2], v3 = s4[3];
            u16x8 w0, w1;
            w0[0]=f2bf(v0.x); w0[1]=f2bf(v0.y); w0[2]=f2bf(v0.z); w0[3]=f2bf(v0.w);
            w0[4]=f2bf(v1.x); w0[5]=f2bf(v1.y); w0[6]=f2bf(v1.z); w0[7]=f2bf(v1.w);
            w1[0]=f2bf(v2.x); w1[1]=f2bf(v2.y); w1[2]=f2bf(v2.z); w1[3]=f2bf(v2.w);
            w1[4]=f2bf(v3.x); w1[5]=f2bf(v3.y); w1[6]=f2bf(v3.z); w1[7]=f2bf(v3.w);
            *(u16x8*)&smA[ar * LDT + aseg]     = w0;
            *(u16x8*)&smA[ar * LDT + aseg + 8] = w1;
        }
        // stage B (already bf16)
        {
            const u16x8* s8 = (const u16x8*)(bptr + k0);
            u16x8 b0 = s8[0], b1 = s8[1], b2 = s8[2], b3 = s8[3];
            *(u16x8*)&smB[bn * LDT + bhalf]      = b0;
            *(u16x8*)&smB[bn * LDT + bhalf + 8]  = b1;
            *(u16x8*)&smB[bn * LDT + bhalf + 16] = b2;
            *(u16x8*)&smB[bn * LDT + bhalf + 24] = b3;
        }
        __syncthreads();
        #pragma unroll
        for (int ks = 0; ks < 64; ks += 32) {
            bf16x8 af = *(const bf16x8*)&smA[(wid * 16 + l15) * LDT + ks + quad * 8];
            #pragma unroll
            for (int t = 0; t < 8; t++) {
                bf16x8 bf = *(const bf16x8*)&smB[(t * 16 + l15) * LDT + ks + quad * 8];
                acc[t] = __builtin_amdgcn_mfma_f32_16x16x32_bf16(af, bf, acc[t], 0, 0, 0);
            }
        }
        __syncthreads();
    }

    // epilogue: regs -> LDS (bf16, [64][EPS]) -> coalesced global
    #pragma unroll
    for (int t = 0; t < 8; t++)
        #pragma unroll
        for (int rg = 0; rg < 4; rg++)
            smB[(wid * 16 + quad * 4 + rg) * EPS + t * 16 + l15] = f2bf(acc[t][rg]);
    __syncthreads();
    const int orow = tid >> 2, oc0 = (tid & 3) * 32;
    if (row0 + orow < M) {
        unsigned short* dst = Y + (long)(row0 + orow) * 128 + oc0;
        #pragma unroll
        for (int i = 0; i < 4; i++)
            *(u16x8*)(dst + i * 8) = *(const u16x8*)&smB[orow * EPS + oc0 + i * 8];
    }
}

// ---------------- SpMM on y (bf16, 128-wide): neigh = A * y ----------------
// 4 waves/block, one dst row per wave; lane covers 2 cols (ushort2).
__global__ __launch_bounds__(256) void k_spmm2(const unsigned short* __restrict__ y,
                                               const int* __restrict__ offsets,
                                               const int* __restrict__ csr_col,
                                               const float* __restrict__ csr_val,
                                               unsigned short* __restrict__ neigh) {
    const int tid = threadIdx.x, lane = tid & 63, wid = tid >> 6;
    const int row = blockIdx.x * 4 + wid;
    const int start = offsets[row], end = offsets[row + 1];
    float a0 = 0.f, a1 = 0.f;
    for (int e = start; e < end; e++) {
        int c = csr_col[e];
        float v = csr_val[e];
        unsigned pk = *(const unsigned*)(y + (long)c * 128 + lane * 2);
        float f0 = __builtin_bit_cast(float, pk << 16);
        float f1 = __builtin_bit_cast(float, pk & 0xffff0000u);
        a0 = fmaf(v, f0, a0);
        a1 = fmaf(v, f1, a1);
    }
    unsigned out = (unsigned)f2bf(a0) | ((unsigned)f2bf(a1) << 16);
    *(unsigned*)(neigh + (long)row * 128 + lane * 2) = out;
}

// ---------------- epilogue: bias + ELU + layernorm + affine ----------------
#define RROWS 8
__global__ __launch_bounds__(256) void k_epi(const unsigned short* __restrict__ selfp,
                                             const unsigned short* __restrict__ neigh,
                                             const float* __restrict__ bw,
                                             const float* __restrict__ bb,
                                             const float* __restrict__ scale,
                                             const float* __restrict__ offs,
                                             float* __restrict__ out) {
    __shared__ float red[RROWS][256];
    __shared__ float mean_s[RROWS], rstd_s[RROWS];
    const int tid = threadIdx.x;
    const int row0 = blockIdx.x * RROWS;
    const bool self = tid < 128;
    const int j = self ? tid : tid - 128;
    const float bias = self ? bb[j] : bw[j];
    const unsigned short* src = self ? selfp : neigh;

    float e[RROWS];
    #pragma unroll
    for (int r = 0; r < RROWS; r++) {
        float v = bf2f(src[(long)(row0 + r) * 128 + j]) + bias;
        e[r] = v > 0.f ? v : expm1f(v);
        red[r][tid] = e[r];
    }
    __syncthreads();

    const int rg = tid >> 5, l32 = tid & 31;
    float s = 0.f, s2 = 0.f;
    #pragma unroll
    for (int c = l32; c < 256; c += 32) { float v = red[rg][c]; s += v; s2 += v * v; }
    #pragma unroll
    for (int o = 16; o > 0; o >>= 1) {
        s  += __shfl_down(s,  o, 32);
        s2 += __shfl_down(s2, o, 32);
    }
    if (l32 == 0) {
        float m = s * (1.f / 256.f);
        float var = s2 * (1.f / 256.f) - m * m;
        mean_s[rg] = m;
        rstd_s[rg] = rsqrtf(var + 1e-9f);
    }
    __syncthreads();

    float sc = scale[tid], of = offs[tid];
    #pragma unroll
    for (int r = 0; r < RROWS; r++)
        out[(long)(row0 + r) * 256 + tid] = (e[r] - mean_s[r]) * rstd_s[r] * sc + of;
}

extern "C" void kernel_launch(void* const* d_in, const int* in_sizes, int n_in,
                              void* d_out, int out_size, void* d_ws, size_t ws_size,
                              hipStream_t stream) {
    const float* x     = (const float*)d_in[0];
    const int*   erows = (const int*)  d_in[1];
    const int*   ecols = (const int*)  d_in[2];
    const float* evals = (const float*)d_in[3];
    const int*   sn    = (const int*)  d_in[4];
    const float* Ww    = (const float*)d_in[5];
    const float* bw    = (const float*)d_in[6];
    const float* Wb    = (const float*)d_in[7];
    const float* bb    = (const float*)d_in[8];
    const float* scale = (const float*)d_in[9];
    const float* offs  = (const float*)d_in[10];
    float* out = (float*)d_out;

    char* ws = (char*)d_ws;
    int*   counts  = (int*)  (ws + WS_COUNTS);
    int*   cursor  = (int*)  (ws + WS_CURSOR);
    int*   offsets = (int*)  (ws + WS_OFFSETS);
    int*   csr_col = (int*)  (ws + WS_CSRCOL);
    float* csr_val = (float*)(ws + WS_CSRVAL);
    int*   bsum    = (int*)  (ws + WS_BSUM);
    unsigned short* Wtw   = (unsigned short*)(ws + WS_WTW);
    unsigned short* Wtb   = (unsigned short*)(ws + WS_WTB);
    unsigned short* neigh = (unsigned short*)(ws + WS_NEIGH);
    unsigned short* selfp = (unsigned short*)(ws + WS_SELF);
    unsigned short* ybuf  = (unsigned short*)d_out;   // y staged in d_out (51.2 MB)

    hipMemsetAsync(ws, 0, 409600, stream);            // counts + cursor

    k_hist   <<<3125, 256, 0, stream>>>(erows, counts);
    k_scan1  <<<49, 256, 0, stream>>>(counts, offsets, bsum);
    k_scan2  <<<1, 64, 0, stream>>>(bsum);
    k_scan3  <<<49, 256, 0, stream>>>(offsets, bsum);
    k_scatter<<<3125, 256, 0, stream>>>(erows, ecols, evals, offsets, cursor, csr_col, csr_val);
    k_wprep  <<<256, 256, 0, stream>>>(Ww, Wb, Wtw, Wtb);
    // y = x @ W_w  (all 200000 rows) -> d_out as bf16
    k_gemm   <<<3125, 256, 0, stream>>>(x, nullptr, Wtw, ybuf, N_SRC);
    // neigh = A * y
    k_spmm2  <<<12500, 256, 0, stream>>>(ybuf, offsets, csr_col, csr_val, neigh);
    // self = x[sn] @ W_b
    k_gemm   <<<782, 256, 0, stream>>>(x, sn, Wtb, selfp, N_DST);
    // bias + ELU + LN + affine -> out
    k_epi    <<<N_DST / RROWS, 256, 0, stream>>>(selfp, neigh, bw, bb, scale, offs, out);
}